// Round 7
// baseline (159.138 us; speedup 1.0000x reference)
//
#include <hip/hip_runtime.h>
#include <math.h>

#define BB 2
#define NN 8192
#define NT 256
#define MAXJB 32            // ceil(NN/256) worst-case j-tiles per sample
#define NCOV (BB * NN / NT) // 64 cov-stat blocks

// ws layout (floats):
#define ACC_OFF 0           // BB*32 floats
#define CNT_OFF 64          // 2 uints (compaction counters)
#define DONE_OFF 66         // 1 uint (k23f gate counter)
#define CDATA_OFF 80        // BB*NN float4
#define PM_OFF (CDATA_OFF + BB * NN * 4)
#define PARTIAL_OFF (PM_OFF + BB * NN)   // [MAXJB][BB*NN][3] floats (~6.3 MB)

// acc layout per sample:
// 0 ref_sum, 1 con_sum, 2 n_pred, 3 spx, 4 spy, 5 spz, 6 n_gt, 7 bm_sum,
// 8..13 cov(xx,xy,xz,yy,yz,zz), 14 sum_dm, 15 sum_d2m, 16 max_dm(bits)

__device__ __forceinline__ float wave_sum(float v) {
#pragma unroll
    for (int o = 32; o > 0; o >>= 1) v += __shfl_xor(v, o, 64);
    return v;
}

__device__ __forceinline__ void wave_atomic_add(float* addr, float v) {
    v = wave_sum(v);
    if ((threadIdx.x & 63) == 0) atomicAdd(addr, v);
}

__device__ __forceinline__ void wave_atomic_max_nonneg(float* addr, float v) {
#pragma unroll
    for (int o = 32; o > 0; o >>= 1) v = fmaxf(v, __shfl_xor(v, o, 64));
    if ((threadIdx.x & 63) == 0) atomicMax((unsigned int*)addr, __float_as_uint(v));
}

__device__ __forceinline__ float acc_ld(const float* p) {
    return __hip_atomic_load(p, __ATOMIC_RELAXED, __HIP_MEMORY_SCOPE_AGENT);
}

__global__ void kz(float* ws) {
    int t = threadIdx.x;
    if (t < 80) ws[t] = 0.f;    // acc + cnts + done
}

// per-point pass + boundary compaction; 64 blocks x 256 threads (R5-proven shape)
__global__ void __launch_bounds__(NT) k1(const float* __restrict__ logits, const float* __restrict__ olog,
                                         const float* __restrict__ h, const int* __restrict__ tgt,
                                         const float* __restrict__ pts, float* __restrict__ ws) {
    int gid = blockIdx.x * NT + threadIdx.x;
    int b = gid >> 13;
    int lane = threadIdx.x & 63;

    const float* L = logits + (size_t)gid * 3;
    float l0 = L[0], l1 = L[1], l2 = L[2];
    const float* O = olog + (size_t)gid * 3;
    float o0 = O[0], o1 = O[1], o2 = O[2];
    float hp = h[gid];
    int t = tgt[gid];
    const float* P = pts + (size_t)gid * 3;
    float px = P[0], py = P[1], pz = P[2];

    float m = fmaxf(l0, fmaxf(l1, l2));
    float e0 = __expf(l0 - m), e1 = __expf(l1 - m), e2 = __expf(l2 - m);
    float s = e0 + e1 + e2;
    float inv = 1.f / s;
    float p0 = e0 * inv, p1 = e1 * inv, p2 = e2 * inv;
    float ls = __logf(s);
    float lt = (t == 0) ? l0 : ((t == 1) ? l1 : l2);
    float nll = -(lt - m - ls);

    float mo = fmaxf(o0, fmaxf(o1, o2));
    float f0 = __expf(o0 - mo), f1 = __expf(o1 - mo), f2 = __expf(o2 - mo);
    float so = 1.f / (f0 + f1 + f2);
    float q0 = f0 * so, q1 = f1 * so, q2 = f2 * so;

    float con = (p0 - q0) * (p0 - q0) + (p1 - q1) * (p1 - q1) + (p2 - q2) * (p2 - q2);

    float bm = (hp > 0.3f && hp < 0.7f) ? 1.f : 0.f;
    float refc = nll * (1.f + bm);
    float pred = (l2 > l0 && l2 > l1) ? 1.f : 0.f;
    float gt = (t == 2) ? 1.f : 0.f;

    // wave-aggregated compaction: one atomic per wave
    unsigned long long mask = __ballot(bm > 0.f);
    unsigned int base = 0;
    if (lane == 0 && mask)
        base = atomicAdd(((unsigned int*)(ws + CNT_OFF)) + b, (unsigned int)__popcll(mask));
    base = __shfl((int)base, 0, 64);
    if (bm > 0.f) {
        unsigned int idx = base + __popcll(mask & ((1ull << lane) - 1ull));
        ((float4*)(ws + CDATA_OFF))[(size_t)b * NN + idx] = make_float4(px, py, pz, p2);
    }
    ws[PM_OFF + gid] = pred;

    float* a = ws + ACC_OFF + b * 32;
    wave_atomic_add(a + 0, refc);
    wave_atomic_add(a + 1, con);
    wave_atomic_add(a + 2, pred);
    wave_atomic_add(a + 3, pred * px);
    wave_atomic_add(a + 4, pred * py);
    wave_atomic_add(a + 5, pred * pz);
    wave_atomic_add(a + 6, gt);
    wave_atomic_add(a + 7, bm);
}

// role-split: cov blocks + pairwise tiles + gated tail (var-reduce + finalize)
__global__ void __launch_bounds__(NT) k23f(const float* __restrict__ pts, float* __restrict__ ws,
                                           float* __restrict__ out) {
    unsigned int* cnts = (unsigned int*)(ws + CNT_OFF);
    int M0 = (int)cnts[0], M1 = (int)cnts[1];
    int JB0 = (M0 + 255) >> 8, JB1 = (M1 + 255) >> 8;
    unsigned int expected = NCOV + JB0 * JB0 + JB1 * JB1;

    __shared__ float4 sj[256];
    __shared__ float red[8];
    __shared__ int lastflag;

    int bid = blockIdx.x;
    bool part;

    if (bid < NCOV) {
        // ---- covariance + distance stats (center from k1) ----
        int gid = bid * NT + threadIdx.x;
        int b = gid >> 13;
        float* a = ws + ACC_OFF + b * 32;

        float n = a[2];
        float nz = fmaxf(n, 1.f);
        float cx = a[3] / nz, cy = a[4] / nz, cz = a[5] / nz;

        const float* P = pts + (size_t)gid * 3;
        float dx = P[0] - cx, dy = P[1] - cy, dz = P[2] - cz;
        float mM = ws[PM_OFF + gid];

        float mx = dx * mM, my = dy * mM, mz = dz * mM;
        float d = sqrtf(dx * dx + dy * dy + dz * dz + 1e-12f);
        float dm = d * mM;

        wave_atomic_add(a + 8,  mx * mx);
        wave_atomic_add(a + 9,  mx * my);
        wave_atomic_add(a + 10, mx * mz);
        wave_atomic_add(a + 11, my * my);
        wave_atomic_add(a + 12, my * mz);
        wave_atomic_add(a + 13, mz * mz);
        wave_atomic_add(a + 14, dm);
        wave_atomic_add(a + 15, d * dm);
        wave_atomic_max_nonneg(a + 16, dm);
        part = true;
    } else {
        // ---- pairwise ball-query tile (branchless, sentinel-padded) ----
        int tile = bid - NCOV;
        int b   = tile / (MAXJB * MAXJB);
        int rel = tile % (MAXJB * MAXJB);
        int ib = rel / MAXJB, jb = rel % MAXJB;
        int M = b ? M1 : M0;
        part = (ib * 256 < M) && (jb * 256 < M);
        if (part) {
            const float4* cd = (const float4*)(ws + CDATA_OFF) + (size_t)b * NN;
            int i = ib * 256 + (int)threadIdx.x;
            bool act = i < M;
            float4 me = cd[act ? i : 0];
            float xi = act ? me.x : 1e9f;

            int j = jb * 256 + (int)threadIdx.x;
            sj[threadIdx.x] = (j < M) ? cd[j] : make_float4(1e9f, 1e9f, 1e9f, 0.f);
            __syncthreads();

            float cnt = 0.f, s1 = 0.f, s2 = 0.f;
#pragma unroll 8
            for (int k = 0; k < 256; k++) {
                float4 v = sj[k];
                float dx = xi - v.x, dy = me.y - v.y, dz = me.z - v.z;
                float d2 = dx * dx + dy * dy + dz * dz;
                float wv = (d2 < 0.0025f) ? 1.f : 0.f;
                cnt += wv; s1 += wv * v.w; s2 += wv * (v.w * v.w);
            }
            // [jb][gid][3]: coalesced across i for fixed jb
            float* p = ws + PARTIAL_OFF + ((size_t)jb * (BB * NN) + (size_t)b * NN + i) * 3;
            p[0] = cnt; p[1] = s1; p[2] = s2;
        }
    }

    if (!part) return;            // block-uniform: inactive tiles don't gate

    // ---- gate: last active block does var-reduce + finalize ----
    __syncthreads();
    __threadfence();
    if (threadIdx.x == 0)
        lastflag = (atomicAdd((unsigned int*)(ws + DONE_OFF), 1u) == expected - 1u) ? 1 : 0;
    __syncthreads();
    if (!lastflag) return;

    float smn[BB], smd[BB];
#pragma unroll
    for (int b2 = 0; b2 < BB; b2++) {
        int M = b2 ? M1 : M0;
        int JB = (M + 255) >> 8;
        float vsum = 0.f, vcnt = 0.f;
        for (int i = (int)threadIdx.x; i < M; i += NT) {
            float cnt = 0.f, s1 = 0.f, s2 = 0.f;
            for (int jb = 0; jb < JB; jb++) {
                const float* p = ws + PARTIAL_OFF + ((size_t)jb * (BB * NN) + (size_t)b2 * NN + i) * 3;
                cnt += acc_ld(p); s1 += acc_ld(p + 1); s2 += acc_ld(p + 2);
            }
            float var = (s2 - s1 * s1 / fmaxf(cnt, 1.f)) / fmaxf(cnt - 1.f, 1.f);
            float valid = (cnt > 1.f) ? 1.f : 0.f;
            vsum += var * valid; vcnt += valid;
        }
        vsum = wave_sum(vsum); vcnt = wave_sum(vcnt);
        if ((threadIdx.x & 63) == 0) {
            red[(threadIdx.x >> 6) * 2]     = vsum;
            red[(threadIdx.x >> 6) * 2 + 1] = vcnt;
        }
        __syncthreads();
        if (threadIdx.x == 0) {
            smn[b2] = red[0] + red[2] + red[4] + red[6];
            smd[b2] = red[1] + red[3] + red[5] + red[7];
        }
        __syncthreads();
    }

    if (threadIdx.x != 0) return;

    double tot = 0.0;
    for (int bb = 0; bb < BB; bb++) {
        const float* ab = ws + ACC_OFF + bb * 32;
        float av[17];
        for (int k = 0; k < 17; k++) av[k] = acc_ld(ab + k);

        double refm = (double)av[0] / NN;
        double conm = (double)av[1] / (NN * 3);
        double n = av[2];
        double nz = fmax(n, 1.0);

        double shape = 0.0;
        if (n >= 10.0) {
            double cxx = av[8] / nz, cxy = av[9] / nz, cxz = av[10] / nz;
            double cyy = av[11] / nz, cyz = av[12] / nz, czz = av[13] / nz;
            double q = (cxx + cyy + czz) / 3.0;
            double p1 = cxy * cxy + cxz * cxz + cyz * cyz;
            double p2 = (cxx - q) * (cxx - q) + (cyy - q) * (cyy - q) + (czz - q) * (czz - q) + 2.0 * p1;
            double p = sqrt(fmax(p2, 0.0) / 6.0);
            double ev0, ev1, ev2;
            if (p < 1e-30) { ev0 = ev1 = ev2 = q; }
            else {
                double b00 = (cxx - q) / p, b11 = (cyy - q) / p, b22 = (czz - q) / p;
                double b01 = cxy / p, b02 = cxz / p, b12 = cyz / p;
                double det = b00 * (b11 * b22 - b12 * b12)
                           - b01 * (b01 * b22 - b12 * b02)
                           + b02 * (b01 * b12 - b11 * b02);
                double r = det / 2.0;
                r = fmin(1.0, fmax(-1.0, r));
                double phi = acos(r) / 3.0;
                double e1 = q + 2.0 * p * cos(phi);
                double e3 = q + 2.0 * p * cos(phi + 2.0943951023931953);
                double e2 = 3.0 * q - e1 - e3;
                ev2 = e1; ev1 = e2; ev0 = e3;
            }
            double aa = ev2 + 1e-8;
            double r1 = ev1 / aa - 1.0, r0 = ev0 / aa - 1.0;
            shape = r1 * r1 + r0 * r0;
        }

        double sdm = av[14], sd2m = av[15], maxd = av[16];
        double varc = (sd2m - sdm * sdm / nz) / fmax(n - 1.0, 1.0);
        double conn = (n >= 5.0) ? varc / (maxd + 1e-8) : 0.0;

        double sm = (av[7] >= 5.0) ? (double)smn[bb] / fmax((double)smd[bb], 1.0) : 0.0;

        double pv = av[2], gv = av[6];
        double vol = (pv - gv) * (pv - gv);
        double rel = fabs(pv - gv) / fmax(gv, 1.0);
        double size = (gv > 0.0) ? vol + 0.5 * rel : vol;

        tot += 0.3 * refm + 0.2 * conm + 0.5 * shape + 0.3 * sm + 0.8 * size + 0.6 * conn;
    }
    out[0] = (float)(tot / BB);
}

extern "C" void kernel_launch(void* const* d_in, const int* in_sizes, int n_in,
                              void* d_out, int out_size, void* d_ws, size_t ws_size,
                              hipStream_t stream) {
    const float* logits = (const float*)d_in[0];
    const float* olog   = (const float*)d_in[1];
    const float* h      = (const float*)d_in[2];
    const int*   tgt    = (const int*)d_in[3];
    const float* pts    = (const float*)d_in[4];
    float* out = (float*)d_out;
    float* ws  = (float*)d_ws;

    kz<<<1, 128, 0, stream>>>(ws);
    k1<<<BB * NN / NT, NT, 0, stream>>>(logits, olog, h, tgt, pts, ws);
    k23f<<<NCOV + BB * MAXJB * MAXJB, NT, 0, stream>>>(pts, ws, out);
}

// Round 8
// 49.006 us; speedup vs baseline: 3.2473x; 3.2473x over previous
//
#include <hip/hip_runtime.h>
#include <math.h>

#define BB 2
#define NN 8192
#define NT 256
#define MAXJB 32            // ceil(NN/256) worst-case j-tiles per sample
#define NCOV (BB * NN / NT) // 64 cov-stat blocks (32 per sample)

// ws layout (floats):
#define SM_OFF 0            // 4 floats: smooth {num,den} per sample (atomic)
#define CNT_OFF 4           // 2 uints: compaction counters
#define DONE_OFF 6          // 1 uint: k45 gate
#define P1_OFF 16           // [64][8] k1 per-block partials
#define P2_OFF (P1_OFF + 64 * 8)        // [64][9] cov per-block partials (8 sums + max)
#define CDATA_OFF 1168                   // BB*NN float4 (aligned)
#define PM_OFF (CDATA_OFF + BB * NN * 4)
#define PARTIAL_OFF (PM_OFF + BB * NN)   // [MAXJB][BB*NN][3] floats (~6.3 MB)

// p1 values: 0=ref_sum 1=con_sum 2=n_pred 3=spx 4=spy 5=spz 6=n_gt 7=bm_sum
// p2 values: 0..5=cov(xx,xy,xz,yy,yz,zz) 6=sum_dm 7=sum_d2m 8=max_dm

__device__ __forceinline__ float wave_sum(float v) {
#pragma unroll
    for (int o = 32; o > 0; o >>= 1) v += __shfl_xor(v, o, 64);
    return v;
}

__device__ __forceinline__ float wave_max(float v) {
#pragma unroll
    for (int o = 32; o > 0; o >>= 1) v = fmaxf(v, __shfl_xor(v, o, 64));
    return v;
}

__device__ __forceinline__ float acc_ld(const float* p) {
    return __hip_atomic_load(p, __ATOMIC_RELAXED, __HIP_MEMORY_SCOPE_AGENT);
}

__global__ void kz(float* ws) {
    if (threadIdx.x < 8) ws[threadIdx.x] = 0.f;   // smacc + cnts + done
}

// per-point pass + boundary compaction; 64 blocks x 256
__global__ void __launch_bounds__(NT) k1(const float* __restrict__ logits, const float* __restrict__ olog,
                                         const float* __restrict__ h, const int* __restrict__ tgt,
                                         const float* __restrict__ pts, float* __restrict__ ws) {
    int gid = blockIdx.x * NT + threadIdx.x;
    int b = gid >> 13;
    int lane = threadIdx.x & 63;
    int wid = threadIdx.x >> 6;

    const float* L = logits + (size_t)gid * 3;
    float l0 = L[0], l1 = L[1], l2 = L[2];
    const float* O = olog + (size_t)gid * 3;
    float o0 = O[0], o1 = O[1], o2 = O[2];
    float hp = h[gid];
    int t = tgt[gid];
    const float* P = pts + (size_t)gid * 3;
    float px = P[0], py = P[1], pz = P[2];

    float m = fmaxf(l0, fmaxf(l1, l2));
    float e0 = __expf(l0 - m), e1 = __expf(l1 - m), e2 = __expf(l2 - m);
    float s = e0 + e1 + e2;
    float inv = 1.f / s;
    float p0 = e0 * inv, p1 = e1 * inv, p2 = e2 * inv;
    float ls = __logf(s);
    float lt = (t == 0) ? l0 : ((t == 1) ? l1 : l2);
    float nll = -(lt - m - ls);

    float mo = fmaxf(o0, fmaxf(o1, o2));
    float f0 = __expf(o0 - mo), f1 = __expf(o1 - mo), f2 = __expf(o2 - mo);
    float so = 1.f / (f0 + f1 + f2);
    float q0 = f0 * so, q1 = f1 * so, q2 = f2 * so;

    float con = (p0 - q0) * (p0 - q0) + (p1 - q1) * (p1 - q1) + (p2 - q2) * (p2 - q2);

    float bm = (hp > 0.3f && hp < 0.7f) ? 1.f : 0.f;
    float refc = nll * (1.f + bm);
    float pred = (l2 > l0 && l2 > l1) ? 1.f : 0.f;
    float gt = (t == 2) ? 1.f : 0.f;

    // ---- block-aggregated compaction: ONE atomic per block ----
    __shared__ unsigned int wcnt[4], woff[4];
    unsigned long long mask = __ballot(bm > 0.f);
    if (lane == 0) wcnt[wid] = (unsigned int)__popcll(mask);
    __syncthreads();
    if (threadIdx.x == 0) {
        unsigned int c0 = wcnt[0], c1 = wcnt[1], c2 = wcnt[2], c3 = wcnt[3];
        unsigned int tot = c0 + c1 + c2 + c3;
        unsigned int base = tot ? atomicAdd(((unsigned int*)(ws + CNT_OFF)) + b, tot) : 0u;
        woff[0] = base; woff[1] = base + c0; woff[2] = base + c0 + c1; woff[3] = base + c0 + c1 + c2;
    }
    __syncthreads();
    if (bm > 0.f) {
        unsigned int idx = woff[wid] + (unsigned int)__popcll(mask & ((1ull << lane) - 1ull));
        ((float4*)(ws + CDATA_OFF))[(size_t)b * NN + idx] = make_float4(px, py, pz, p2);
    }
    ws[PM_OFF + gid] = pred;

    // ---- block-reduce 8 values -> p1buf[blk][8] (no atomics) ----
    __shared__ float r1[4][8];
    float vals[8] = { refc, con, pred, pred * px, pred * py, pred * pz, gt, bm };
#pragma unroll
    for (int k = 0; k < 8; k++) {
        float v = wave_sum(vals[k]);
        if (lane == 0) r1[wid][k] = v;
    }
    __syncthreads();
    if (threadIdx.x < 8) {
        int k = threadIdx.x;
        ws[P1_OFF + blockIdx.x * 8 + k] = r1[0][k] + r1[1][k] + r1[2][k] + r1[3][k];
    }
}

// role-split: 64 cov blocks + 2048 pairwise tiles
__global__ void __launch_bounds__(NT) k23(const float* __restrict__ pts, float* __restrict__ ws) {
    unsigned int* cnts = (unsigned int*)(ws + CNT_OFF);
    int bid = blockIdx.x;

    if (bid < NCOV) {
        // ---- cov/dist stats; center from p1buf sums ----
        int gid = bid * NT + threadIdx.x;
        int b = bid >> 5;
        int lane = threadIdx.x & 63;
        int wid = threadIdx.x >> 6;

        __shared__ float cen[4][32];
        __shared__ float cenv[4];
        if (threadIdx.x < 128) {
            int k = threadIdx.x & 3, c = threadIdx.x >> 2;
            cen[k][c] = ws[P1_OFF + (b * 32 + c) * 8 + 2 + k];   // n, spx, spy, spz
        }
        __syncthreads();
        if (threadIdx.x < 4) {
            float s = 0.f;
            for (int c = 0; c < 32; c++) s += cen[threadIdx.x][c];
            cenv[threadIdx.x] = s;
        }
        __syncthreads();
        float n = cenv[0];
        float nz = fmaxf(n, 1.f);
        float cx = cenv[1] / nz, cy = cenv[2] / nz, cz = cenv[3] / nz;

        const float* P = pts + (size_t)gid * 3;
        float dx = P[0] - cx, dy = P[1] - cy, dz = P[2] - cz;
        float mM = ws[PM_OFF + gid];

        float mx = dx * mM, my = dy * mM, mz = dz * mM;
        float d = sqrtf(dx * dx + dy * dy + dz * dz + 1e-12f);
        float dm = d * mM;

        // block-reduce 8 sums + 1 max -> p2buf[bid][9]
        __shared__ float r2[4][9];
        float vals[8] = { mx * mx, mx * my, mx * mz, my * my, my * mz, mz * mz, dm, d * dm };
#pragma unroll
        for (int k = 0; k < 8; k++) {
            float v = wave_sum(vals[k]);
            if (lane == 0) r2[wid][k] = v;
        }
        {
            float v = wave_max(dm);
            if (lane == 0) r2[wid][8] = v;
        }
        __syncthreads();
        if (threadIdx.x < 8) {
            int k = threadIdx.x;
            ws[P2_OFF + bid * 9 + k] = r2[0][k] + r2[1][k] + r2[2][k] + r2[3][k];
        } else if (threadIdx.x == 8) {
            ws[P2_OFF + bid * 9 + 8] = fmaxf(fmaxf(r2[0][8], r2[1][8]), fmaxf(r2[2][8], r2[3][8]));
        }
        return;
    }

    // ---- pairwise ball-query tile (branchless, sentinel-padded) ----
    int tile = bid - NCOV;
    int b   = tile / (MAXJB * MAXJB);
    int rel = tile % (MAXJB * MAXJB);
    int ib = rel / MAXJB, jb = rel % MAXJB;
    int M = (int)cnts[b];
    if (ib * 256 >= M || jb * 256 >= M) return;     // uniform block exit

    const float4* cd = (const float4*)(ws + CDATA_OFF) + (size_t)b * NN;
    int i = ib * 256 + (int)threadIdx.x;
    bool act = i < M;
    float4 me = cd[act ? i : 0];
    float xi = act ? me.x : 1e9f;

    __shared__ float4 sj[256];
    int j = jb * 256 + (int)threadIdx.x;
    sj[threadIdx.x] = (j < M) ? cd[j] : make_float4(1e9f, 1e9f, 1e9f, 0.f);
    __syncthreads();

    float cnt = 0.f, s1 = 0.f, s2 = 0.f;
#pragma unroll 8
    for (int k = 0; k < 256; k++) {
        float4 v = sj[k];
        float dx = xi - v.x, dy = me.y - v.y, dz = me.z - v.z;
        float d2 = dx * dx + dy * dy + dz * dz;
        float wv = (d2 < 0.0025f) ? 1.f : 0.f;
        cnt += wv; s1 += wv * v.w; s2 += wv * (v.w * v.w);
    }
    float* p = ws + PARTIAL_OFF + ((size_t)jb * (BB * NN) + (size_t)b * NN + i) * 3;
    p[0] = cnt; p[1] = s1; p[2] = s2;
}

// smoothness var-reduce + gated finalize; 64 blocks x 256
__global__ void __launch_bounds__(NT) k45(float* __restrict__ ws, float* __restrict__ out) {
    int gid = blockIdx.x * NT + threadIdx.x;
    int b = blockIdx.x >> 5, i = gid & (NN - 1);
    int lane = threadIdx.x & 63;
    int wid = threadIdx.x >> 6;
    unsigned int* cnts = (unsigned int*)(ws + CNT_OFF);
    int M = (int)cnts[b];

    // ---- per-i smoothness variance (plain cached loads; partial from k23) ----
    float vsum = 0.f, vcnt = 0.f;
    if (i < M) {
        int JB = (M + 255) >> 8;
        float cnt = 0.f, s1 = 0.f, s2 = 0.f;
        for (int jb = 0; jb < JB; jb++) {
            const float* p = ws + PARTIAL_OFF + ((size_t)jb * (BB * NN) + (size_t)b * NN + i) * 3;
            cnt += p[0]; s1 += p[1]; s2 += p[2];
        }
        float var = (s2 - s1 * s1 / fmaxf(cnt, 1.f)) / fmaxf(cnt - 1.f, 1.f);
        float valid = (cnt > 1.f) ? 1.f : 0.f;
        vsum = var * valid; vcnt = valid;
    }
    __shared__ float red[4][2];
    vsum = wave_sum(vsum); vcnt = wave_sum(vcnt);
    if (lane == 0) { red[wid][0] = vsum; red[wid][1] = vcnt; }
    __syncthreads();
    if (threadIdx.x == 0) {
        float ns = red[0][0] + red[1][0] + red[2][0] + red[3][0];
        float nc = red[0][1] + red[1][1] + red[2][1] + red[3][1];
        if (ns != 0.f) atomicAdd(ws + SM_OFF + b * 2, ns);
        if (nc != 0.f) atomicAdd(ws + SM_OFF + b * 2 + 1, nc);
    }

    // ---- gate: last of 64 blocks finalizes ----
    __syncthreads();
    __threadfence();
    __shared__ int lastflag;
    if (threadIdx.x == 0)
        lastflag = (atomicAdd((unsigned int*)(ws + DONE_OFF), 1u) == 63u) ? 1 : 0;
    __syncthreads();
    if (!lastflag) return;

    // parallel-reduce p1buf[64][8], p2buf[64][9] (written by earlier kernels -> plain loads)
    __shared__ float t1[BB][8][32];
    __shared__ float t2[BB][9][32];
    __shared__ float ft1[BB][8];
    __shared__ float ft2[BB][9];
    int t = threadIdx.x;
    if (t < 64) {
        int c = t & 31, bb = t >> 5;
#pragma unroll
        for (int k = 0; k < 8; k++) t1[bb][k][c] = ws[P1_OFF + (bb * 32 + c) * 8 + k];
#pragma unroll
        for (int k = 0; k < 9; k++) t2[bb][k][c] = ws[P2_OFF + (bb * 32 + c) * 9 + k];
    }
    __syncthreads();
    if (t < 16) {
        int bb = t >> 3, k = t & 7;
        float s = 0.f;
        for (int c = 0; c < 32; c++) s += t1[bb][k][c];
        ft1[bb][k] = s;
    } else if (t < 34) {
        int idx = t - 16, bb = idx / 9, k = idx % 9;
        if (k < 8) {
            float s = 0.f;
            for (int c = 0; c < 32; c++) s += t2[bb][k][c];
            ft2[bb][k] = s;
        } else {
            float s = 0.f;
            for (int c = 0; c < 32; c++) s = fmaxf(s, t2[bb][8][c]);
            ft2[bb][8] = s;
        }
    }
    __syncthreads();
    if (t != 0) return;

    double tot = 0.0;
    for (int bb = 0; bb < BB; bb++) {
        double refm = (double)ft1[bb][0] / NN;
        double conm = (double)ft1[bb][1] / (NN * 3);
        double n = ft1[bb][2];
        double nz = fmax(n, 1.0);

        double shape = 0.0;
        if (n >= 10.0) {
            double cxx = ft2[bb][0] / nz, cxy = ft2[bb][1] / nz, cxz = ft2[bb][2] / nz;
            double cyy = ft2[bb][3] / nz, cyz = ft2[bb][4] / nz, czz = ft2[bb][5] / nz;
            double q = (cxx + cyy + czz) / 3.0;
            double p1 = cxy * cxy + cxz * cxz + cyz * cyz;
            double p2 = (cxx - q) * (cxx - q) + (cyy - q) * (cyy - q) + (czz - q) * (czz - q) + 2.0 * p1;
            double p = sqrt(fmax(p2, 0.0) / 6.0);
            double ev0, ev1, ev2;
            if (p < 1e-30) { ev0 = ev1 = ev2 = q; }
            else {
                double b00 = (cxx - q) / p, b11 = (cyy - q) / p, b22 = (czz - q) / p;
                double b01 = cxy / p, b02 = cxz / p, b12 = cyz / p;
                double det = b00 * (b11 * b22 - b12 * b12)
                           - b01 * (b01 * b22 - b12 * b02)
                           + b02 * (b01 * b12 - b11 * b02);
                double r = det / 2.0;
                r = fmin(1.0, fmax(-1.0, r));
                double phi = acos(r) / 3.0;
                double e1 = q + 2.0 * p * cos(phi);
                double e3 = q + 2.0 * p * cos(phi + 2.0943951023931953);
                double e2 = 3.0 * q - e1 - e3;
                ev2 = e1; ev1 = e2; ev0 = e3;
            }
            double aa = ev2 + 1e-8;
            double r1 = ev1 / aa - 1.0, r0 = ev0 / aa - 1.0;
            shape = r1 * r1 + r0 * r0;
        }

        double sdm = ft2[bb][6], sd2m = ft2[bb][7], maxd = ft2[bb][8];
        double varc = (sd2m - sdm * sdm / nz) / fmax(n - 1.0, 1.0);
        double conn = (n >= 5.0) ? varc / (maxd + 1e-8) : 0.0;

        double smn = (double)acc_ld(ws + SM_OFF + bb * 2);
        double smd = (double)acc_ld(ws + SM_OFF + bb * 2 + 1);
        double sm = (ft1[bb][7] >= 5.0) ? smn / fmax(smd, 1.0) : 0.0;

        double pv = ft1[bb][2], gv = ft1[bb][6];
        double vol = (pv - gv) * (pv - gv);
        double rel = fabs(pv - gv) / fmax(gv, 1.0);
        double size = (gv > 0.0) ? vol + 0.5 * rel : vol;

        tot += 0.3 * refm + 0.2 * conm + 0.5 * shape + 0.3 * sm + 0.8 * size + 0.6 * conn;
    }
    out[0] = (float)(tot / BB);
}

extern "C" void kernel_launch(void* const* d_in, const int* in_sizes, int n_in,
                              void* d_out, int out_size, void* d_ws, size_t ws_size,
                              hipStream_t stream) {
    const float* logits = (const float*)d_in[0];
    const float* olog   = (const float*)d_in[1];
    const float* h      = (const float*)d_in[2];
    const int*   tgt    = (const int*)d_in[3];
    const float* pts    = (const float*)d_in[4];
    float* out = (float*)d_out;
    float* ws  = (float*)d_ws;

    kz<<<1, 64, 0, stream>>>(ws);
    k1<<<BB * NN / NT, NT, 0, stream>>>(logits, olog, h, tgt, pts, ws);
    k23<<<NCOV + BB * MAXJB * MAXJB, NT, 0, stream>>>(pts, ws);
    k45<<<NCOV, NT, 0, stream>>>(ws, out);
}